// Round 10
// baseline (342.951 us; speedup 1.0000x reference)
//
#include <hip/hip_runtime.h>
#include <hip/hip_bf16.h>
#include <cstdint>

typedef float f32x4 __attribute__((ext_vector_type(4)));
typedef float f32x16 __attribute__((ext_vector_type(16)));
typedef short bf16x8 __attribute__((ext_vector_type(8)));

__device__ __forceinline__ unsigned short f32_to_bf16_rne(float f) {
  unsigned int u = __float_as_uint(f);
  return (unsigned short)((u + 0x7FFFu + ((u >> 16) & 1u)) >> 16);
}

#define GLOAD_LDS16(gptr, lptr)                                                             \
  __builtin_amdgcn_global_load_lds((const __attribute__((address_space(1))) unsigned int*)(gptr), \
                                   (__attribute__((address_space(3))) unsigned int*)(lptr), 16, 0, 0)

// ---------------- fused f32 -> bf16 for all 5 operands (8 elems / thread) ----------------
__global__ __launch_bounds__(256) void cvt_all(const float* __restrict__ wv,
                                               const float* __restrict__ q,
                                               const float* __restrict__ v,
                                               const float* __restrict__ wq,
                                               const float* __restrict__ wo,
                                               unsigned short* __restrict__ wvb,
                                               unsigned short* __restrict__ qb,
                                               unsigned short* __restrict__ vb,
                                               unsigned short* __restrict__ wqb,
                                               unsigned short* __restrict__ wob) {
  int i = blockIdx.x * 256 + threadIdx.x;  // chunk of 8 floats
  const float* src;
  unsigned short* dst;
  int off;
  if (i < 4194304)      { src = wv; dst = wvb; off = i; }
  else if (i < 4456448) { src = q;  dst = qb;  off = i - 4194304; }
  else if (i < 4718592) { src = v;  dst = vb;  off = i - 4456448; }
  else if (i < 4849664) { src = wq; dst = wqb; off = i - 4718592; }
  else                  { src = wo; dst = wob; off = i - 4849664; }
  const float4* s = (const float4*)src;
  float4 a = s[2 * off], b = s[2 * off + 1];
  uint4 o;
  o.x = (unsigned)f32_to_bf16_rne(a.x) | ((unsigned)f32_to_bf16_rne(a.y) << 16);
  o.y = (unsigned)f32_to_bf16_rne(a.z) | ((unsigned)f32_to_bf16_rne(a.w) << 16);
  o.z = (unsigned)f32_to_bf16_rne(b.x) | ((unsigned)f32_to_bf16_rne(b.y) << 16);
  o.w = (unsigned)f32_to_bf16_rne(b.z) | ((unsigned)f32_to_bf16_rne(b.w) << 16);
  ((uint4*)dst)[off] = o;
}

// ---------------- fuzzy membership + softmax: LDS-staged rules, one head per block --------
__global__ __launch_bounds__(256) void fuzzy2_k(const float* __restrict__ qf,
                                                const float* __restrict__ rk,
                                                const float* __restrict__ rw,
                                                float* __restrict__ attn) {
  __shared__ float lk[32][65];
  __shared__ float lc[32][65];
  const int tid = threadIdx.x;
  const int h = blockIdx.y;
  const int mbase = blockIdx.x * 128;

  for (int idx = tid; idx < 2048; idx += 256) {
    int r = idx >> 6, d = idx & 63;
    lk[r][d] = rk[(size_t)(h * 32 + r) * 64 + d];
    float w = rw[(size_t)(h * 32 + r) * 64 + d];
    lc[r][d] = 0.0078125f / (w * w);
  }
  __syncthreads();

  const int g = tid >> 5;
  const int r = tid & 31;
#pragma unroll 1
  for (int it = 0; it < 16; ++it) {
    int m = mbase + it * 8 + g;
    const float* qrow = qf + (size_t)m * 1024 + h * 64;
    float acc = 0.f;
#pragma unroll
    for (int d0 = 0; d0 < 64; d0 += 4) {
      float4 q4 = *(const float4*)(qrow + d0);
      const float* qp = (const float*)&q4;
#pragma unroll
      for (int j = 0; j < 4; ++j) {
        float diff = qp[j] - lk[r][d0 + j];
        acc += lc[r][d0 + j] * diff * diff;
      }
    }
    float z = -acc;
    float mx = z;
#pragma unroll
    for (int mask = 16; mask >= 1; mask >>= 1) mx = fmaxf(mx, __shfl_xor(mx, mask));
    float e = __expf(z - mx);
    float s = e;
#pragma unroll
    for (int mask = 16; mask >= 1; mask >>= 1) s += __shfl_xor(s, mask);
    attn[(size_t)m * 512 + h * 32 + r] = e / s;
  }
}

// ---------------- small bf16 GEMM (64x64 tile, 512 blocks, ~8/CU): C = (A@W^T+b)*scale ----
__global__ __launch_bounds__(256) void gemm_bt64(const unsigned short* __restrict__ A,
                                                 const unsigned short* __restrict__ W,
                                                 const float* __restrict__ bias, float scale,
                                                 int M, int N, int K, float* __restrict__ Cf) {
  constexpr int BK = 32;
  __shared__ unsigned short As[2][64 * BK];
  __shared__ unsigned short Bs[2][64 * BK];
  const int tid = threadIdx.x;
  const int wid = tid >> 6;
  const int lane = tid & 63;
  const int l15 = lane & 15;
  const int l4 = lane >> 4;
  const int bm = blockIdx.y * 64;
  const int bn = blockIdx.x * 64;
  const int wr = (wid >> 1) * 32;
  const int wc = (wid & 1) * 32;

  f32x4 acc[2][2];
#pragma unroll
  for (int i = 0; i < 2; ++i)
#pragma unroll
    for (int j = 0; j < 2; ++j) acc[i][j] = (f32x4){0.f, 0.f, 0.f, 0.f};

  const int nk = K / BK;
  auto stage = [&](int buf, int kt) {
    int c = tid;  // 256 chunks of 16B per 4KB tile
    int row = c >> 2, ch = c & 3;
    int sch = ch ^ ((row >> 1) & 3);
    GLOAD_LDS16(A + (size_t)(bm + row) * K + kt * BK + sch * 8, &As[buf][c * 8]);
    GLOAD_LDS16(W + (size_t)(bn + row) * K + kt * BK + sch * 8, &Bs[buf][c * 8]);
  };

  stage(0, 0);
  __syncthreads();

  for (int kt = 0; kt < nk; ++kt) {
    const int cur = kt & 1;
    if (kt + 1 < nk) stage(cur ^ 1, kt + 1);
    bf16x8 a[2], b[2];
#pragma unroll
    for (int mi = 0; mi < 2; ++mi) {
      int rl = wr + mi * 16 + l15;
      int ph = (rl * 64 + l4 * 16) ^ ((((unsigned)rl >> 1) & 3) << 4);
      a[mi] = *(const bf16x8*)((const char*)&As[cur][0] + ph);
    }
#pragma unroll
    for (int ni = 0; ni < 2; ++ni) {
      int rl = wc + ni * 16 + l15;
      int ph = (rl * 64 + l4 * 16) ^ ((((unsigned)rl >> 1) & 3) << 4);
      b[ni] = *(const bf16x8*)((const char*)&Bs[cur][0] + ph);
    }
#pragma unroll
    for (int mi = 0; mi < 2; ++mi)
#pragma unroll
      for (int ni = 0; ni < 2; ++ni)
        acc[mi][ni] = __builtin_amdgcn_mfma_f32_16x16x32_bf16(a[mi], b[ni], acc[mi][ni], 0, 0, 0);
    __syncthreads();
  }

#pragma unroll
  for (int mi = 0; mi < 2; ++mi) {
#pragma unroll
    for (int ni = 0; ni < 2; ++ni) {
      int gm = bm + wr + mi * 16 + l4 * 4;
      int gn = bn + wc + ni * 16 + l15;
      float bval = bias[gn];
#pragma unroll
      for (int q = 0; q < 4; ++q)
        Cf[(size_t)(gm + q) * N + gn] = (acc[mi][ni][q] + bval) * scale;
    }
  }
}

// ---------------- GEMM2: 256x256 tile, BK=32, 4-buf, 32x32x16 MFMA, fused agg -------------
// A: value bf16 (2048 x 1024), W: Wv bf16 (32768 x 1024)
// X[b,h,s,d] = scale * sum_r attn[m,h,r] * (A[m,:]@W[h*2048+d*32+r,:] + bias)
// Round-8 schedule (best measured: 1 barrier/slab, stage T+2, counted vmcnt(4), reads
// interleaved in cluster) with v_mfma_f32_32x32x16_bf16: MFMA pipe demand/slab drops
// 1242->1033 cyc (m119: 2495 vs 2178 TF), instruction count halves, LDS traffic equal.
// A/B frag: lane holds row/col (lane&31), 8 K-elems at (lane>>5)*8 within each K16 half.
// C/D frag (m74/m101): col=lane&31, row=(reg&3)+8*(reg>>2)+4*(lane>>5).
// vmcnt ledger: 4 gload_lds per slab-stage; BODY(T) issues stage(T+2): queue =
// stage(T+1)[4] + stage(T+2)[4] -> vmcnt(4) waits exactly tile T+1. Body 30: vmcnt(0).
__global__ __launch_bounds__(512) void gemm2_k(const unsigned short* __restrict__ A,
                                               const unsigned short* __restrict__ W,
                                               const float* __restrict__ bias, float scale,
                                               const float* __restrict__ attn,
                                               unsigned short* __restrict__ X) {
  constexpr int K = 1024, BK = 32;
  extern __shared__ unsigned short lds[];  // A: 4 x 8192, B: 4 x 8192 ushorts = 128 KB
  unsigned short* Asl = lds;
  unsigned short* Bsl = lds + 4 * 8192;
  const int tid = threadIdx.x;
  const int wid = tid >> 6, lane = tid & 63;
  const int l31 = lane & 31, lh = lane >> 5;
  const int wm = wid >> 2, wn = wid & 3;  // wave tile 128x64

  // XCD-aware bijective swizzle: contiguous col-tile strip per XCD (B-panel L2 reuse)
  int orig = blockIdx.x;
  int swz = (orig & 7) * 128 + (orig >> 3);
  const int bm = (swz & 7) * 256, bn = (swz >> 3) * 256;

  auto stageA = [&](int buf, int kt) {
#pragma unroll
    for (int i = 0; i < 2; ++i) {
      int c = i * 512 + tid;  // 1024 chunks of 16B; slab = 256 rows x 4 chunks
      int row = c >> 2, ch = c & 3;
      int sch = ch ^ ((row >> 1) & 3);  // inverse swizzle on SOURCE (rule #21)
      GLOAD_LDS16(A + (size_t)(bm + row) * K + kt * BK + sch * 8, Asl + buf * 8192 + c * 8);
    }
  };
  auto stageB = [&](int buf, int kt) {
#pragma unroll
    for (int i = 0; i < 2; ++i) {
      int c = i * 512 + tid;
      int row = c >> 2, ch = c & 3;
      int sch = ch ^ ((row >> 1) & 3);
      GLOAD_LDS16(W + (size_t)(bn + row) * K + kt * BK + sch * 8, Bsl + buf * 8192 + c * 8);
    }
  };

  f32x16 acc[4][2];
#pragma unroll
  for (int i = 0; i < 4; ++i)
#pragma unroll
    for (int j = 0; j < 2; ++j) acc[i][j] = (f32x16)(0.f);

  // a[rb][kh]: rows wm*128+rb*32+l31, K-chunk kh*2+lh.  b[cb][kh]: cols wn*64+cb*32+l31.
  bf16x8 a0[4][2], a1[4][2], b0[2][2], b1[2][2];

#define PH32(rl, ch) ((((rl) * 64) + (ch) * 16) ^ ((((unsigned)(rl) >> 1) & 3) << 4))

  // BODY: compute tile Tt from (aC,bC); stage Tt+2; load tile Tt+1 frags into (aN,bN),
  // 12 ds_reads interleaved into the 16-MFMA cluster (8 a-reads in kh0, 4 b-reads in kh1).
#define BODY(aC, aN, bC, bN, Tt, DO_STAGE, WN)                                            \
  do {                                                                                    \
    if (DO_STAGE) { stageA(((Tt) + 2) & 3, (Tt) + 2); stageB(((Tt) + 2) & 3, (Tt) + 2); } \
    asm volatile("s_waitcnt vmcnt(" #WN ")" ::: "memory");                                \
    __builtin_amdgcn_s_barrier();                                                         \
    {                                                                                     \
      const char* _ab = (const char*)(Asl + (((Tt) + 1) & 3) * 8192);                     \
      const char* _bb = (const char*)(Bsl + (((Tt) + 1) & 3) * 8192);                     \
      __builtin_amdgcn_s_setprio(1);                                                      \
      _Pragma("unroll") for (int rb = 0; rb < 4; ++rb)                                    \
        _Pragma("unroll") for (int cb = 0; cb < 2; ++cb) {                                \
          acc[rb][cb] = __builtin_amdgcn_mfma_f32_32x32x16_bf16(aC[rb][0], bC[cb][0],     \
                                                                acc[rb][cb], 0, 0, 0);    \
          int i = rb * 2 + cb;                                                            \
          aN[i >> 1][i & 1] =                                                             \
              *(const bf16x8*)(_ab + PH32(wm * 128 + (i >> 1) * 32 + l31,                 \
                                          (i & 1) * 2 + lh));                             \
        }                                                                                 \
      _Pragma("unroll") for (int rb = 0; rb < 4; ++rb)                                    \
        _Pragma("unroll") for (int cb = 0; cb < 2; ++cb) {                                \
          acc[rb][cb] = __builtin_amdgcn_mfma_f32_32x32x16_bf16(aC[rb][1], bC[cb][1],     \
                                                                acc[rb][cb], 0, 0, 0);    \
          int i = rb * 2 + cb;                                                            \
          if (i < 4)                                                                      \
            bN[i >> 1][i & 1] =                                                           \
                *(const bf16x8*)(_bb + PH32(wn * 64 + (i >> 1) * 32 + l31,                \
                                            (i & 1) * 2 + lh));                           \
        }                                                                                 \
      __builtin_amdgcn_s_setprio(0);                                                      \
    }                                                                                     \
    asm volatile("s_waitcnt lgkmcnt(0)" ::: "memory");                                    \
    __builtin_amdgcn_sched_barrier(0);                                                    \
  } while (0)

  // prologue: stage slabs 0,1 (8 loads); vmcnt(4) -> slab 0 landed; load tile-0 frags
  stageA(0, 0); stageB(0, 0);
  stageA(1, 1); stageB(1, 1);
  asm volatile("s_waitcnt vmcnt(4)" ::: "memory");
  __builtin_amdgcn_s_barrier();
#pragma unroll
  for (int cb = 0; cb < 2; ++cb)
#pragma unroll
    for (int kh = 0; kh < 2; ++kh)
      b0[cb][kh] = *(const bf16x8*)((const char*)Bsl + PH32(wn * 64 + cb * 32 + l31, kh * 2 + lh));
#pragma unroll
  for (int rb = 0; rb < 4; ++rb)
#pragma unroll
    for (int kh = 0; kh < 2; ++kh)
      a0[rb][kh] = *(const bf16x8*)((const char*)Asl + PH32(wm * 128 + rb * 32 + l31, kh * 2 + lh));
  asm volatile("s_waitcnt lgkmcnt(0)" ::: "memory");
  __builtin_amdgcn_sched_barrier(0);

  // bodies 0..29 (stage reaches tile 31 at body 29)
  for (int T = 0; T < 30; T += 2) {
    BODY(a0, a1, b0, b1, T, 1, 4);
    BODY(a1, a0, b1, b0, (T + 1), 1, 4);
  }
  // body 30: no stage; drain stage(31); load tile-31 frags into (a1,b1)
  BODY(a0, a1, b0, b1, 30, 0, 0);
  // tail: tile 31, registers only
  __builtin_amdgcn_s_setprio(1);
#pragma unroll
  for (int kh = 0; kh < 2; ++kh)
#pragma unroll
    for (int rb = 0; rb < 4; ++rb)
#pragma unroll
      for (int cb = 0; cb < 2; ++cb)
        acc[rb][cb] = __builtin_amdgcn_mfma_f32_32x32x16_bf16(a1[rb][kh], b1[cb][kh],
                                                              acc[rb][cb], 0, 0, 0);
  __builtin_amdgcn_s_setprio(0);
#undef BODY
#undef PH32

  // ---- fused rule-aggregation epilogue (32x32 C/D layout) ----
  // col = bn + wn*64 + cb*32 + l31 -> rule r = l31, d = dbase + cb.
  // row m = bm + wm*128 + rb*32 + (reg&3) + 8*(reg>>2) + 4*lh.
  const int h = bn >> 11;                          // 2048 cols per head
  const int dbase = ((bn & 2047) + wn * 64) >> 5;  // even
  const float bv0 = bias[bn + wn * 64 + l31];
  const float bv1 = bias[bn + wn * 64 + 32 + l31];
#pragma unroll
  for (int rb = 0; rb < 4; ++rb) {
    const int m0 = bm + wm * 128 + rb * 32 + 4 * lh;
#pragma unroll
    for (int reg = 0; reg < 16; ++reg) {
      int m = m0 + (reg & 3) + 8 * (reg >> 2);
      float w = attn[(size_t)m * 512 + h * 32 + l31];
      float v0 = (acc[rb][0][reg] + bv0) * w;
      float v1 = (acc[rb][1][reg] + bv1) * w;
#pragma unroll
      for (int mask = 1; mask < 32; mask <<= 1) {
        v0 += __shfl_xor(v0, mask);
        v1 += __shfl_xor(v1, mask);
      }
      if (l31 == 0) {
        int bb = m >> 10, s = m & 1023;
        size_t base = (((size_t)(bb * 16 + h)) * 1024 + s) * 64;
        unsigned lo = f32_to_bf16_rne(v0 * scale);
        unsigned hi = f32_to_bf16_rne(v1 * scale);
        ((unsigned*)X)[(base + dbase) >> 1] = lo | (hi << 16);
      }
    }
  }
}

extern "C" void kernel_launch(void* const* d_in, const int* in_sizes, int n_in, void* d_out,
                              int out_size, void* d_ws, size_t ws_size, hipStream_t stream) {
  const float* query = (const float*)d_in[0];
  const float* value = (const float*)d_in[2];
  const float* rk = (const float*)d_in[3];
  const float* rw = (const float*)d_in[4];
  const float* Wq = (const float*)d_in[5];
  const float* bq = (const float*)d_in[6];
  const float* Wv = (const float*)d_in[7];
  const float* bv = (const float*)d_in[8];
  const float* Wo = (const float*)d_in[9];
  const float* bo = (const float*)d_in[10];
  float* out = (float*)d_out;

  const float scale = 0.125f;

  char* p = (char*)d_ws;
  unsigned short* Wv_b = (unsigned short*)p; p += (size_t)33554432 * 2;
  unsigned short* Aq_b = (unsigned short*)p; p += (size_t)2097152 * 2;
  unsigned short* Av_b = (unsigned short*)p; p += (size_t)2097152 * 2;
  unsigned short* Wq_b = (unsigned short*)p; p += (size_t)1048576 * 2;
  unsigned short* Wo_b = (unsigned short*)p; p += (size_t)1048576 * 2;
  float* qf = (float*)p;   p += (size_t)2097152 * 4;
  float* attn = (float*)p; p += (size_t)1048576 * 4;
  unsigned short* X = (unsigned short*)p;

  cvt_all<<<19456, 256, 0, stream>>>(Wv, query, value, Wq, Wo, Wv_b, Aq_b, Av_b, Wq_b, Wo_b);

  // GEMM1: qf = (query @ Wq^T + bq) * scale   (2048 x 1024), 512 blocks
  gemm_bt64<<<dim3(16, 32), 256, 0, stream>>>(Aq_b, Wq_b, bq, scale, 2048, 1024, 1024, qf);
  // fuzzy membership + softmax
  fuzzy2_k<<<dim3(16, 16), 256, 0, stream>>>(qf, rk, rw, attn);
  // GEMM2 fused (256^2, 4-buf, 32x32x16 MFMA, 128KB dynamic LDS)
  hipFuncSetAttribute((const void*)gemm2_k, hipFuncAttributeMaxDynamicSharedMemorySize, 131072);
  gemm2_k<<<1024, 512, 131072, stream>>>(Av_b, Wv_b, bv, scale, attn, X);
  // GEMM3: out = X @ Wo^T + bo
  gemm_bt64<<<dim3(16, 32), 256, 0, stream>>>(X, Wo_b, bo, 1.0f, 2048, 1024, 1024, out);
}